// Round 3
// baseline (144.135 us; speedup 1.0000x reference)
//
#include <hip/hip_runtime.h>
#include <math.h>

// B=4, N=512, C=D=256, K=20, rows=2048
//
// ws layout (float offsets) — alpha overlaps Wt (used sequentially):
//   WtL   [0, 65536)         W_l^T [c][d]        (k_transpose -> k_proj)
//   WtR   [65536, 131072)
//   alpha [0, 1048576)       [row][512]          (k_pair -> k_topk, clobbers Wt)
//   XL    [1048576, +524288) [row][d]  row-major
//   XRt   [1572864, +524288) [b][d][j] d-major (transposed for coalesced k_pair reads)
//   Av    [2097152, +2048)   dot(att, XL[row])
//   Bv    [2099200, +2048)   dot(att, XR[row])
//
// out (float): [0,40960) index_i | [40960,81920) index_j | [81920,122880) attention

__global__ __launch_bounds__(256) void k_transpose(const float* __restrict__ Wl,
                                                   const float* __restrict__ Wr,
                                                   float* __restrict__ WtL,
                                                   float* __restrict__ WtR) {
    const int d = blockIdx.x, c = threadIdx.x;  // coalesced read of W[d][:]
    if (blockIdx.y == 0) WtL[c * 256 + d] = Wl[d * 256 + c];
    else                 WtR[c * 256 + d] = Wr[d * 256 + c];
}

// 512 wgs x 256 thr; wg = 4 rows, thread t = output feature d. (unchanged from R2)
__global__ __launch_bounds__(256) void k_proj(const float* __restrict__ x,
        const float* __restrict__ WtL, const float* __restrict__ WtR,
        const float* __restrict__ bl, const float* __restrict__ br,
        const float* __restrict__ att,
        float* __restrict__ XL, float* __restrict__ XRt,
        float* __restrict__ Av, float* __restrict__ Bv) {
    __shared__ float xs[4 * 256];
    __shared__ float red[32];
    const int tid = threadIdx.x;
    const int R = blockIdx.x * 4;

    ((float4*)xs)[tid] = ((const float4*)(x + (size_t)R * 256))[tid];
    __syncthreads();

    float accL[4] = {0.f, 0.f, 0.f, 0.f}, accR[4] = {0.f, 0.f, 0.f, 0.f};
    for (int c = 0; c < 256; c += 4) {
        const float wl0 = WtL[(c + 0) * 256 + tid];
        const float wl1 = WtL[(c + 1) * 256 + tid];
        const float wl2 = WtL[(c + 2) * 256 + tid];
        const float wl3 = WtL[(c + 3) * 256 + tid];
        const float wr0 = WtR[(c + 0) * 256 + tid];
        const float wr1 = WtR[(c + 1) * 256 + tid];
        const float wr2 = WtR[(c + 2) * 256 + tid];
        const float wr3 = WtR[(c + 3) * 256 + tid];
#pragma unroll
        for (int r = 0; r < 4; ++r) {
            const float4 xv = *(const float4*)&xs[r * 256 + c];
            accL[r] = fmaf(xv.x, wl0, accL[r]);
            accL[r] = fmaf(xv.y, wl1, accL[r]);
            accL[r] = fmaf(xv.z, wl2, accL[r]);
            accL[r] = fmaf(xv.w, wl3, accL[r]);
            accR[r] = fmaf(xv.x, wr0, accR[r]);
            accR[r] = fmaf(xv.y, wr1, accR[r]);
            accR[r] = fmaf(xv.z, wr2, accR[r]);
            accR[r] = fmaf(xv.w, wr3, accR[r]);
        }
    }

    const float blv = bl[tid], brv = br[tid], atv = att[tid];
    float xlv[4], xrv[4], pa[4], pb[4];
#pragma unroll
    for (int r = 0; r < 4; ++r) {
        xlv[r] = accL[r] + blv;
        xrv[r] = accR[r] + brv;
        XL[(size_t)(R + r) * 256 + tid] = xlv[r];
        pa[r] = atv * xlv[r];
        pb[r] = atv * xrv[r];
    }
    const int b = R >> 9, jr = R & 511;
    *(float4*)&XRt[((size_t)(b * 256 + tid)) * 512 + jr] =
        make_float4(xrv[0], xrv[1], xrv[2], xrv[3]);

#pragma unroll
    for (int r = 0; r < 4; ++r) {
#pragma unroll
        for (int off = 32; off; off >>= 1) {
            pa[r] += __shfl_xor(pa[r], off);
            pb[r] += __shfl_xor(pb[r], off);
        }
    }
    const int lane = tid & 63, wv = tid >> 6;
    if (lane == 0) {
#pragma unroll
        for (int r = 0; r < 4; ++r) {
            red[r * 8 + wv] = pa[r];
            red[r * 8 + 4 + wv] = pb[r];
        }
    }
    __syncthreads();
    if (tid < 8) {
        const int r = tid >> 1, side = tid & 1;
        const float* p = &red[r * 8 + side * 4];
        const float s = p[0] + p[1] + p[2] + p[3];
        if (side == 0) Av[R + r] = s; else Bv[R + r] = s;
    }
}

// 1024 wgs x 256 thr. wg = (i-octet, j-quarter of 128). Thread: j = jl, d-half = h.
// Double-buffered xr prefetch; xl/att via uniform s_loads; one LDS merge barrier.
__global__ __launch_bounds__(256) void k_pair(const float* __restrict__ XL,
        const float* __restrict__ XRt, const float* __restrict__ Av,
        const float* __restrict__ Bv, const float* __restrict__ att,
        float* __restrict__ alpha) {
    __shared__ float mrg[128 * 8];     // [jl][i] partial sums from h=1
    const int tid = threadIdx.x;
    const int g = blockIdx.x;          // 0..1023
    const int jq = g & 3;              // j-quarter
    const int io = g >> 2;             // 0..255 i-octet
    const int b = io >> 6;
    const int R = b * 512 + (io & 63) * 8;
    const int jl = tid & 127;
    const int h = tid >> 7;            // d-half (wave-uniform)
    const int j = jq * 128 + jl;       // j within batch
    const int dbase = h * 128;

    const float* __restrict__ XLr = XL + (size_t)R * 256;  // uniform
    const float* __restrict__ xrp = XRt + ((size_t)(b * 256 + dbase)) * 512 + j;

    float acc[8];
#pragma unroll
    for (int i = 0; i < 8; ++i) acc[i] = 0.f;

    float xrbuf[2][8];
#pragma unroll
    for (int dd = 0; dd < 8; ++dd) xrbuf[0][dd] = xrp[dd * 512];  // preload chunk 0

#pragma unroll
    for (int ch = 0; ch < 16; ++ch) {
        const float* cur = xrbuf[ch & 1];
        float* nxt = xrbuf[(ch + 1) & 1];
        if (ch < 15) {                                  // prefetch next chunk
            const float* p = xrp + (size_t)(ch + 1) * 8 * 512;
#pragma unroll
            for (int dd = 0; dd < 8; ++dd) nxt[dd] = p[dd * 512];
        }
        const int d = dbase + ch * 8;
        const float4 at0 = *(const float4*)&att[d];      // uniform -> s_load
        const float4 at1 = *(const float4*)&att[d + 4];
#pragma unroll
        for (int i = 0; i < 8; ++i) {
            const float4 xa = *(const float4*)&XLr[i * 256 + d];      // uniform
            const float4 xb = *(const float4*)&XLr[i * 256 + d + 4];
            acc[i] = fmaf(at0.x, fabsf(xa.x + cur[0]), acc[i]);
            acc[i] = fmaf(at0.y, fabsf(xa.y + cur[1]), acc[i]);
            acc[i] = fmaf(at0.z, fabsf(xa.z + cur[2]), acc[i]);
            acc[i] = fmaf(at0.w, fabsf(xa.w + cur[3]), acc[i]);
            acc[i] = fmaf(at1.x, fabsf(xb.x + cur[4]), acc[i]);
            acc[i] = fmaf(at1.y, fabsf(xb.y + cur[5]), acc[i]);
            acc[i] = fmaf(at1.z, fabsf(xb.z + cur[6]), acc[i]);
            acc[i] = fmaf(at1.w, fabsf(xb.w + cur[7]), acc[i]);
        }
    }

    // merge d-halves: h=1 dumps partials, h=0 adds and finishes
    if (h == 1) {
        *(float4*)&mrg[jl * 8 + 0] = make_float4(acc[0], acc[1], acc[2], acc[3]);
        *(float4*)&mrg[jl * 8 + 4] = make_float4(acc[4], acc[5], acc[6], acc[7]);
    }
    __syncthreads();
    if (h == 0) {
        const float4 m0 = *(const float4*)&mrg[jl * 8 + 0];
        const float4 m1 = *(const float4*)&mrg[jl * 8 + 4];
        acc[0] += m0.x; acc[1] += m0.y; acc[2] += m0.z; acc[3] += m0.w;
        acc[4] += m1.x; acc[5] += m1.y; acc[6] += m1.z; acc[7] += m1.w;
        const float Bj = Bv[b * 512 + j];
#pragma unroll
        for (int i = 0; i < 8; ++i) {
            float a = fmaf(0.4f, acc[i], 0.6f * (Av[R + i] + Bj));
            if (!isfinite(a)) a = 0.f;                  // nan_to_num
            alpha[(size_t)(R + i) * 512 + j] = a;       // coalesced (128-wide)
        }
    }
}

// 512 wgs x 256 thr; one wave per row. top-20 (jax tie-break) + softmax + output.
__global__ __launch_bounds__(256) void k_topk(const float* __restrict__ alpha,
                                              float* __restrict__ out) {
    const int lane = threadIdx.x & 63;
    const int row = blockIdx.x * 4 + (threadIdx.x >> 6);
    const float* ar = alpha + (size_t)row * 512;

    const float4 u0 = *(const float4*)&ar[lane * 8];
    const float4 u1 = *(const float4*)&ar[lane * 8 + 4];
    float v[8] = {u0.x, u0.y, u0.z, u0.w, u1.x, u1.y, u1.z, u1.w};  // j = lane*8 + t

    float myval = 0.f, mmax = 0.f;
    int myidx = 0;
    for (int sel = 0; sel < 20; ++sel) {
        float bv = v[0]; int bt = 0;
#pragma unroll
        for (int t = 1; t < 8; ++t) { if (v[t] > bv) { bv = v[t]; bt = t; } }
        int bj = lane * 8 + bt;
#pragma unroll
        for (int off = 32; off; off >>= 1) {   // butterfly argmax, lower j wins ties
            const float ov = __shfl_xor(bv, off);
            const int   oj = __shfl_xor(bj, off);
            if (ov > bv || (ov == bv && oj < bj)) { bv = ov; bj = oj; }
        }
        if (sel == 0) mmax = bv;
        if (lane == sel) { myval = bv; myidx = bj; }
        if ((bj >> 3) == lane) {
            const int bt2 = bj & 7;
#pragma unroll
            for (int t = 0; t < 8; ++t) if (t == bt2) v[t] = -INFINITY;
        }
    }
    const float e = (lane < 20) ? expf(myval - mmax) : 0.f;
    float s = e;
#pragma unroll
    for (int off = 32; off; off >>= 1) s += __shfl_xor(s, off);
    if (lane < 20) {
        const int base = row * 20 + lane;
        const int b = row >> 9;
        out[base] = (float)row;                        // index_i
        out[40960 + base] = (float)(b * 512 + myidx);  // index_j
        out[81920 + base] = e / s;                     // attention
    }
}

extern "C" void kernel_launch(void* const* d_in, const int* in_sizes, int n_in,
                              void* d_out, int out_size, void* d_ws, size_t ws_size,
                              hipStream_t stream) {
    const float* x   = (const float*)d_in[0];
    const float* Wl  = (const float*)d_in[3];
    const float* bl  = (const float*)d_in[4];
    const float* Wr  = (const float*)d_in[5];
    const float* br  = (const float*)d_in[6];
    const float* att = (const float*)d_in[7];

    float* ws    = (float*)d_ws;
    float* WtL   = ws;
    float* WtR   = ws + 65536;
    float* alpha = ws;                 // overlaps Wt (sequential use)
    float* XL    = ws + 1048576;
    float* XRt   = ws + 1572864;
    float* Av    = ws + 2097152;
    float* Bv    = ws + 2099200;
    float* out   = (float*)d_out;

    k_transpose<<<dim3(256, 2), dim3(256), 0, stream>>>(Wl, Wr, WtL, WtR);
    k_proj<<<dim3(512), dim3(256), 0, stream>>>(x, WtL, WtR, bl, br, att, XL, XRt, Av, Bv);
    k_pair<<<dim3(1024), dim3(256), 0, stream>>>(XL, XRt, Av, Bv, att, alpha);
    k_topk<<<dim3(512), dim3(256), 0, stream>>>(alpha, out);
}

// Round 4
// 122.371 us; speedup vs baseline: 1.1779x; 1.1779x over previous
//
#include <hip/hip_runtime.h>
#include <math.h>

// B=4, N=512, C=D=256, K=20, rows=2048
//
// ws layout (float offsets):
//   WtL   [0, 65536)         W_l^T [c][d]        (k_transpose -> k_proj)
//   WtR   [65536, 131072)
//   XL    [1048576, +524288) [row][d]  row-major
//   XRt   [1572864, +524288) [b][d][j] d-major (transposed for coalesced k_pair reads)
//   Av    [2097152, +2048)   dot(att, XL[row])
//   Bv    [2099200, +2048)   dot(att, XR[row])
//
// out (float): [0,40960) index_i | [40960,81920) index_j | [81920,122880) attention

__global__ __launch_bounds__(256) void k_transpose(const float* __restrict__ Wl,
                                                   const float* __restrict__ Wr,
                                                   float* __restrict__ WtL,
                                                   float* __restrict__ WtR) {
    const int d = blockIdx.x, c = threadIdx.x;  // coalesced read of W[d][:]
    if (blockIdx.y == 0) WtL[c * 256 + d] = Wl[d * 256 + c];
    else                 WtR[c * 256 + d] = Wr[d * 256 + c];
}

// 512 wgs x 256 thr; wg = 4 rows, thread t = output feature d. (unchanged from R2)
__global__ __launch_bounds__(256) void k_proj(const float* __restrict__ x,
        const float* __restrict__ WtL, const float* __restrict__ WtR,
        const float* __restrict__ bl, const float* __restrict__ br,
        const float* __restrict__ att,
        float* __restrict__ XL, float* __restrict__ XRt,
        float* __restrict__ Av, float* __restrict__ Bv) {
    __shared__ float xs[4 * 256];
    __shared__ float red[32];
    const int tid = threadIdx.x;
    const int R = blockIdx.x * 4;

    ((float4*)xs)[tid] = ((const float4*)(x + (size_t)R * 256))[tid];
    __syncthreads();

    float accL[4] = {0.f, 0.f, 0.f, 0.f}, accR[4] = {0.f, 0.f, 0.f, 0.f};
    for (int c = 0; c < 256; c += 4) {
        const float wl0 = WtL[(c + 0) * 256 + tid];
        const float wl1 = WtL[(c + 1) * 256 + tid];
        const float wl2 = WtL[(c + 2) * 256 + tid];
        const float wl3 = WtL[(c + 3) * 256 + tid];
        const float wr0 = WtR[(c + 0) * 256 + tid];
        const float wr1 = WtR[(c + 1) * 256 + tid];
        const float wr2 = WtR[(c + 2) * 256 + tid];
        const float wr3 = WtR[(c + 3) * 256 + tid];
#pragma unroll
        for (int r = 0; r < 4; ++r) {
            const float4 xv = *(const float4*)&xs[r * 256 + c];
            accL[r] = fmaf(xv.x, wl0, accL[r]);
            accL[r] = fmaf(xv.y, wl1, accL[r]);
            accL[r] = fmaf(xv.z, wl2, accL[r]);
            accL[r] = fmaf(xv.w, wl3, accL[r]);
            accR[r] = fmaf(xv.x, wr0, accR[r]);
            accR[r] = fmaf(xv.y, wr1, accR[r]);
            accR[r] = fmaf(xv.z, wr2, accR[r]);
            accR[r] = fmaf(xv.w, wr3, accR[r]);
        }
    }

    const float blv = bl[tid], brv = br[tid], atv = att[tid];
    float xlv[4], xrv[4], pa[4], pb[4];
#pragma unroll
    for (int r = 0; r < 4; ++r) {
        xlv[r] = accL[r] + blv;
        xrv[r] = accR[r] + brv;
        XL[(size_t)(R + r) * 256 + tid] = xlv[r];
        pa[r] = atv * xlv[r];
        pb[r] = atv * xrv[r];
    }
    const int b = R >> 9, jr = R & 511;
    *(float4*)&XRt[((size_t)(b * 256 + tid)) * 512 + jr] =
        make_float4(xrv[0], xrv[1], xrv[2], xrv[3]);

#pragma unroll
    for (int r = 0; r < 4; ++r) {
#pragma unroll
        for (int off = 32; off; off >>= 1) {
            pa[r] += __shfl_xor(pa[r], off);
            pb[r] += __shfl_xor(pb[r], off);
        }
    }
    const int lane = tid & 63, wv = tid >> 6;
    if (lane == 0) {
#pragma unroll
        for (int r = 0; r < 4; ++r) {
            red[r * 8 + wv] = pa[r];
            red[r * 8 + 4 + wv] = pb[r];
        }
    }
    __syncthreads();
    if (tid < 8) {
        const int r = tid >> 1, side = tid & 1;
        const float* p = &red[r * 8 + side * 4];
        const float s = p[0] + p[1] + p[2] + p[3];
        if (side == 0) Av[R + r] = s; else Bv[R + r] = s;
    }
}

// Fused pair + top-k + softmax. 512 wgs x 256 thr; wg = 4 rows x all 512 j.
// Thread: jc = tid&127 (4 j's), h = tid>>7 (d-half). XL/att broadcast from LDS.
__global__ __launch_bounds__(256) void k_pair_topk(const float* __restrict__ XL,
        const float* __restrict__ XRt, const float* __restrict__ Av,
        const float* __restrict__ Bv, const float* __restrict__ att,
        float* __restrict__ out) {
    __shared__ float xls[4 * 256];    // 4 XL rows
    __shared__ float atts[256];
    __shared__ float mrg[16 * 128];   // [i*4+jj][jc] h=1 partials (conflict-free)
    __shared__ float alph[4 * 512];   // final alpha rows
    const int tid = threadIdx.x;
    const int g = blockIdx.x;          // 0..511 = row-quad
    const int R = g * 4;
    const int b = R >> 9;
    const int jc = tid & 127;
    const int h = tid >> 7;            // wave-uniform d-half

    // stage XL rows + att
    ((float4*)xls)[tid] = ((const float4*)(XL + (size_t)R * 256))[tid];
    if (tid < 64) ((float4*)atts)[tid] = ((const float4*)att)[tid];
    __syncthreads();

    const float* xrbase = XRt + ((size_t)(b * 256 + h * 128)) * 512 + jc * 4;
    const int dbase = h * 128;

    float4 acc[4];
#pragma unroll
    for (int i = 0; i < 4; ++i) acc[i] = make_float4(0.f, 0.f, 0.f, 0.f);

    float4 buf[2][8];
#pragma unroll
    for (int dd = 0; dd < 8; ++dd) buf[0][dd] = *(const float4*)(xrbase + dd * 512);

#pragma unroll
    for (int ch = 0; ch < 16; ++ch) {
        const float4* cur = buf[ch & 1];
        float4* nxt = buf[(ch + 1) & 1];
        if (ch < 15) {
            const float* p = xrbase + (size_t)(ch + 1) * 8 * 512;
#pragma unroll
            for (int dd = 0; dd < 8; ++dd) nxt[dd] = *(const float4*)(p + dd * 512);
        }
        const int d = dbase + ch * 8;
        const float4 at0 = *(const float4*)&atts[d];       // LDS broadcast
        const float4 at1 = *(const float4*)&atts[d + 4];
#pragma unroll
        for (int i = 0; i < 4; ++i) {
            const float4 xa = *(const float4*)&xls[i * 256 + d];
            const float4 xb = *(const float4*)&xls[i * 256 + d + 4];
#define PSTEP(XLC, ATC, XR4)                                   \
            acc[i].x = fmaf(ATC, fabsf(XLC + XR4.x), acc[i].x); \
            acc[i].y = fmaf(ATC, fabsf(XLC + XR4.y), acc[i].y); \
            acc[i].z = fmaf(ATC, fabsf(XLC + XR4.z), acc[i].z); \
            acc[i].w = fmaf(ATC, fabsf(XLC + XR4.w), acc[i].w);
            PSTEP(xa.x, at0.x, cur[0])
            PSTEP(xa.y, at0.y, cur[1])
            PSTEP(xa.z, at0.z, cur[2])
            PSTEP(xa.w, at0.w, cur[3])
            PSTEP(xb.x, at1.x, cur[4])
            PSTEP(xb.y, at1.y, cur[5])
            PSTEP(xb.z, at1.z, cur[6])
            PSTEP(xb.w, at1.w, cur[7])
#undef PSTEP
        }
    }

    // merge d-halves through LDS (transposed layout: scalar, conflict-free)
    if (h == 1) {
#pragma unroll
        for (int i = 0; i < 4; ++i) {
            mrg[(i * 4 + 0) * 128 + jc] = acc[i].x;
            mrg[(i * 4 + 1) * 128 + jc] = acc[i].y;
            mrg[(i * 4 + 2) * 128 + jc] = acc[i].z;
            mrg[(i * 4 + 3) * 128 + jc] = acc[i].w;
        }
    }
    __syncthreads();
    if (h == 0) {
        const float4 Bj = *(const float4*)&Bv[b * 512 + jc * 4];
#pragma unroll
        for (int i = 0; i < 4; ++i) {
            const float Ai = Av[R + i];
            float a0 = fmaf(0.4f, acc[i].x + mrg[(i * 4 + 0) * 128 + jc], 0.6f * (Ai + Bj.x));
            float a1 = fmaf(0.4f, acc[i].y + mrg[(i * 4 + 1) * 128 + jc], 0.6f * (Ai + Bj.y));
            float a2 = fmaf(0.4f, acc[i].z + mrg[(i * 4 + 2) * 128 + jc], 0.6f * (Ai + Bj.z));
            float a3 = fmaf(0.4f, acc[i].w + mrg[(i * 4 + 3) * 128 + jc], 0.6f * (Ai + Bj.w));
            if (!isfinite(a0)) a0 = 0.f;   // nan_to_num
            if (!isfinite(a1)) a1 = 0.f;
            if (!isfinite(a2)) a2 = 0.f;
            if (!isfinite(a3)) a3 = 0.f;
            *(float4*)&alph[i * 512 + jc * 4] = make_float4(a0, a1, a2, a3);
        }
    }
    __syncthreads();

    // top-20 + softmax: wave w handles row i=w (4 waves, 4 rows)
    const int lane = tid & 63;
    const int i = tid >> 6;
    const float* ar = &alph[i * 512];
    const float4 u0 = *(const float4*)&ar[lane * 8];
    const float4 u1 = *(const float4*)&ar[lane * 8 + 4];
    float v[8] = {u0.x, u0.y, u0.z, u0.w, u1.x, u1.y, u1.z, u1.w};  // j = lane*8 + t

    float myval = 0.f, mmax = 0.f;
    int myidx = 0;
    for (int sel = 0; sel < 20; ++sel) {
        float bv = v[0]; int bt = 0;
#pragma unroll
        for (int t = 1; t < 8; ++t) { if (v[t] > bv) { bv = v[t]; bt = t; } }
        int bj = lane * 8 + bt;
#pragma unroll
        for (int off = 32; off; off >>= 1) {   // butterfly argmax, lower j wins ties
            const float ov = __shfl_xor(bv, off);
            const int   oj = __shfl_xor(bj, off);
            if (ov > bv || (ov == bv && oj < bj)) { bv = ov; bj = oj; }
        }
        if (sel == 0) mmax = bv;
        if (lane == sel) { myval = bv; myidx = bj; }
        if ((bj >> 3) == lane) {
            const int bt2 = bj & 7;
#pragma unroll
            for (int t = 0; t < 8; ++t) if (t == bt2) v[t] = -INFINITY;
        }
    }
    const float e = (lane < 20) ? expf(myval - mmax) : 0.f;
    float s = e;
#pragma unroll
    for (int off = 32; off; off >>= 1) s += __shfl_xor(s, off);
    if (lane < 20) {
        const int row = R + i;
        const int base = row * 20 + lane;
        out[base] = (float)row;                        // index_i
        out[40960 + base] = (float)(b * 512 + myidx);  // index_j
        out[81920 + base] = e / s;                     // attention
    }
}

extern "C" void kernel_launch(void* const* d_in, const int* in_sizes, int n_in,
                              void* d_out, int out_size, void* d_ws, size_t ws_size,
                              hipStream_t stream) {
    const float* x   = (const float*)d_in[0];
    const float* Wl  = (const float*)d_in[3];
    const float* bl  = (const float*)d_in[4];
    const float* Wr  = (const float*)d_in[5];
    const float* br  = (const float*)d_in[6];
    const float* att = (const float*)d_in[7];

    float* ws    = (float*)d_ws;
    float* WtL   = ws;
    float* WtR   = ws + 65536;
    float* XL    = ws + 1048576;
    float* XRt   = ws + 1572864;
    float* Av    = ws + 2097152;
    float* Bv    = ws + 2099200;
    float* out   = (float*)d_out;

    k_transpose<<<dim3(256, 2), dim3(256), 0, stream>>>(Wl, Wr, WtL, WtR);
    k_proj<<<dim3(512), dim3(256), 0, stream>>>(x, WtL, WtR, bl, br, att, XL, XRt, Av, Bv);
    k_pair_topk<<<dim3(512), dim3(256), 0, stream>>>(XL, XRt, Av, Bv, att, out);
}